// Round 8
// baseline (108.283 us; speedup 1.0000x reference)
//
#include <hip/hip_runtime.h>

// Problem constants
#define BB 8
#define CI 64
#define CO 64
#define NV 40962
#define KN 7
#define KKD 448   // CI*KN

typedef unsigned short u16;
typedef unsigned int u32;

typedef __bf16 bf16x8 __attribute__((ext_vector_type(8)));
typedef float f32x16 __attribute__((ext_vector_type(16)));

__device__ inline u16 f2bf(float f) {
    u32 u = __builtin_bit_cast(u32, f);
    u32 r = (u + 0x7FFFu + ((u >> 16) & 1u)) >> 16;  // RNE
    return (u16)r;
}

// global 16B/lane -> LDS at (wave-uniform base + lane*16); dest linear.
__device__ inline void gload_lds16(const void* g, void* l) {
    __builtin_amdgcn_global_load_lds(
        (const __attribute__((address_space(1))) u32*)g,
        (__attribute__((address_space(3))) u32*)l, 16, 0, 0);
}

// ---------------------------------------------------------------------------
// Kernel 1: transpose + cast: x[b][c][n] f32 -> xTI[n][b][c] bf16.
// Vertex row n = 8 batches x 64 ch x 2B = 1 KB contiguous (the whole point:
// one gathered neighbor = one coalesced 1 KB burst serving all batches).
// ---------------------------------------------------------------------------
__global__ void transpose_x(const float* __restrict__ x, u16* __restrict__ xTI) {
    __shared__ u16 tile[64][72];
    const int b = blockIdx.y;
    const int n0 = blockIdx.x * 64;
    const int tid = threadIdx.x;

#pragma unroll
    for (int i = 0; i < 16; ++i) {
        int flat = i * 256 + tid;
        int c = flat >> 6;
        int nn = flat & 63;
        int n = n0 + nn;
        if (n < NV) {
            float v = __builtin_nontemporal_load(&x[((size_t)b * CI + c) * NV + n]);
            tile[nn][c] = f2bf(v);
        }
    }
    __syncthreads();

#pragma unroll
    for (int i = 0; i < 2; ++i) {
        int flat8 = i * 256 + tid;
        int nn = flat8 >> 3;
        int c0 = (flat8 & 7) * 8;
        int n = n0 + nn;
        if (n < NV) {
            uint4 v = *(const uint4*)&tile[nn][c0];
            *(uint4*)&xTI[((size_t)n * 8 + b) * 64 + c0] = v;   // [n][b][c]
        }
    }
}

// ---------------------------------------------------------------------------
// Kernel 2: pack W into MFMA A-fragment order (bf16)  [layout unchanged]
// Wf byte offset (rg*28 + k*4 + s)*1024 + lane*16
// ---------------------------------------------------------------------------
__global__ void pack_w(const float* __restrict__ W, u16* __restrict__ Wf) {
    int e = blockIdx.x * 256 + threadIdx.x;
    if (e < 2 * 28 * 64 * 8) {
        int j = e & 7;
        int lane = (e >> 3) & 63;
        int sg = e >> 9;
        int s = sg % 28;
        int rg = sg / 28;
        int o = rg * 32 + (lane & 31);
        int kk = s * 16 + ((lane >> 5) << 3) + j;
        int kn = kk >> 6;
        int c = kk & 63;
        Wf[e] = f2bf(W[o * KKD + c * KN + kn]);
    }
}

// ---------------------------------------------------------------------------
// Kernel 3: batch-interleaved gather + MFMA GEMM, ring-3 pipeline (r6 proven).
// grid: 2561 blocks, block 256 = 4 waves (rg 2 x cg 2).
// Tile: 16 vertices x 8 batches = 128 cols x 64 outs. Per k: stage 16 rows
// of 1 KB (one wave-instr per row, fully coalesced); 16 MFMA/block.
// MFMA col = vsub*8 + b (vsub=(lane&31)>>3, b=lane&7).
// LDS slot-swizzle: chunk position = chan_blk ^ b ^ (row&3); applied via
// source permutation on the staging load (dest stays linear) and on ds_read.
// Schedule per iter k: issue A(k+1) -> vmcnt(8) [drains G(k)+A(k), leaves
// G(k+1)+A(k+1)] -> s_barrier -> issue G(k+2) into buf (k+2)%3 -> compute.
// ---------------------------------------------------------------------------
__global__ __launch_bounds__(256, 3) void conv_mfma(
    const u16* __restrict__ xTI, const u16* __restrict__ Wf,
    const int* __restrict__ idx, const float* __restrict__ bias,
    float* __restrict__ out) {
    __shared__ alignas(16) u16 G[3][8192];   // 3 x 16 KB; buffer = 16 rows x 1 KB

    const int bid = blockIdx.x;
    const int n0 = bid * 16;
    const int t = threadIdx.x;
    const int lane = t & 63;
    const int w = t >> 6;        // 0..3
    const int rg = w & 1;
    const int cg = w >> 1;       // 0..1
    const int half = lane >> 5;
    const int seg = lane >> 3;   // batch index on the staging side
    const int sl = lane & 7;     // dest 16B slot within 128B segment

    const char* xbc = (const char*)xTI;
    const char* wfc = (const char*)Wf;
    char* gb = (char*)&G[0][0];

    // wave w stages local rows w*4+i (vertex n0+w*4+i); j wave-uniform
    int jv[4][KN];
#pragma unroll
    for (int i = 0; i < 4; ++i) {
        int v = n0 + w * 4 + i; if (v >= NV) v = NV - 1;
        int4 lo = *(const int4*)(idx + (size_t)v * KN);
        int4 hi = *(const int4*)(idx + (size_t)v * KN + 3);
        jv[i][0] = lo.x; jv[i][1] = lo.y; jv[i][2] = lo.z; jv[i][3] = lo.w;
        jv[i][4] = hi.y; jv[i][5] = hi.z; jv[i][6] = hi.w;
    }

    // staging source pre-swizzle: lane l of row i reads chunk (sl^seg^i)
    u32 srcoff[4];
#pragma unroll
    for (int i = 0; i < 4; ++i)
        srcoff[i] = (u32)(seg * 128) + (u32)((((sl ^ seg ^ i) & 7)) << 4);

    // wave-uniform LDS dest base (HW adds lane*16)
    const u32 dstrow = (u32)((w * 4) * 1024);

    // B-read offsets: row (cg*2+ct)*4+vsub, batch bb, slot (2s+half)^bb^vsub
    const int vsub = (lane & 31) >> 3;
    const int bb = lane & 7;
    u32 rbyte[2][4];
#pragma unroll
    for (int ct = 0; ct < 2; ++ct)
#pragma unroll
        for (int s = 0; s < 4; ++s) {
            int rowv = (cg * 2 + ct) * 4 + vsub;
            int slot = ((s * 2 + half) ^ bb ^ vsub) & 7;
            rbyte[ct][s] = (u32)(rowv * 1024 + bb * 128 + slot * 16);
        }

    const u32 abase = (u32)((rg * 28) * 1024 + lane * 16);

    f32x16 acc0{}, acc1{};

    // ---- prologue: G(0), A(0), G(1)  (issue order pinned for vmcnt) ----
#pragma unroll
    for (int i = 0; i < 4; ++i)
        gload_lds16(xbc + (size_t)jv[i][0] * 1024 + srcoff[i],
                    gb + 0 * 16384 + dstrow + (u32)(i * 1024));
    __builtin_amdgcn_sched_barrier(0);
    uint4 acur0 = *(const uint4*)(wfc + abase + 0 * 1024);
    uint4 acur1 = *(const uint4*)(wfc + abase + 1 * 1024);
    uint4 acur2 = *(const uint4*)(wfc + abase + 2 * 1024);
    uint4 acur3 = *(const uint4*)(wfc + abase + 3 * 1024);
    __builtin_amdgcn_sched_barrier(0);
#pragma unroll
    for (int i = 0; i < 4; ++i)
        gload_lds16(xbc + (size_t)jv[i][1] * 1024 + srcoff[i],
                    gb + 1 * 16384 + dstrow + (u32)(i * 1024));
    __builtin_amdgcn_sched_barrier(0);

#pragma unroll
    for (int k = 0; k < KN; ++k) {
        // ---- issue A(k+1) ----
        uint4 an0, an1, an2, an3;
        if (k + 1 < KN) {
            u32 ab = abase + (u32)((k + 1) * 4 * 1024);
            an0 = *(const uint4*)(wfc + ab + 0 * 1024);
            an1 = *(const uint4*)(wfc + ab + 1 * 1024);
            an2 = *(const uint4*)(wfc + ab + 2 * 1024);
            an3 = *(const uint4*)(wfc + ab + 3 * 1024);
        }
        __builtin_amdgcn_sched_barrier(0);

        // ---- non-draining wait: queue [G(k)4,A(k)4,G(k+1)4,A(k+1)4] ----
        if (k <= 5) asm volatile("s_waitcnt vmcnt(8)" ::: "memory");
        else        asm volatile("s_waitcnt vmcnt(0)" ::: "memory");
        __builtin_amdgcn_sched_barrier(0);
        __builtin_amdgcn_s_barrier();
        __builtin_amdgcn_sched_barrier(0);

        // ---- issue G(k+2) AFTER barrier (ring-3 race-free, r6 proof) ----
        if (k + 2 < KN) {
            u32 db = (u32)(((k + 2) % 3) * 16384);
#pragma unroll
            for (int i = 0; i < 4; ++i)
                gload_lds16(xbc + (size_t)jv[i][k + 2] * 1024 + srcoff[i],
                            gb + db + dstrow + (u32)(i * 1024));
        }
        __builtin_amdgcn_sched_barrier(0);

        // ---- compute on buffer k%3: 2 col-tiles x 4 K-steps = 8 MFMA ----
        const char* gsrc = gb + (u32)((k % 3) * 16384);
#pragma unroll
        for (int s = 0; s < 4; ++s) {
            uint4 b0 = *(const uint4*)(gsrc + rbyte[0][s]);
            uint4 b1 = *(const uint4*)(gsrc + rbyte[1][s]);
            uint4 af = (s == 0) ? acur0 : (s == 1) ? acur1 : (s == 2) ? acur2 : acur3;
            acc0 = __builtin_amdgcn_mfma_f32_32x32x16_bf16(
                __builtin_bit_cast(bf16x8, af), __builtin_bit_cast(bf16x8, b0), acc0, 0, 0, 0);
            acc1 = __builtin_amdgcn_mfma_f32_32x32x16_bf16(
                __builtin_bit_cast(bf16x8, af), __builtin_bit_cast(bf16x8, b1), acc1, 0, 0, 0);
        }

        if (k + 1 < KN) { acur0 = an0; acur1 = an1; acur2 = an2; acur3 = an3; }
    }

    // epilogue: col (vsub,bb) -> out[bb][o][v]; per (bb,o) the block's lanes
    // cover contiguous 16B; full 128B lines come from ct0+ct1 (+L2 merge).
    const int vb = n0 + cg * 8;
#pragma unroll
    for (int r = 0; r < 16; ++r) {
        int rowo = (r & 3) + 8 * (r >> 2) + 4 * half;
        int o = rg * 32 + rowo;
        float bo = bias[o];
        size_t obase = ((size_t)(bb * CO + o)) * NV;
        int v0 = vb + vsub;
        int v1 = vb + 4 + vsub;
        if (v0 < NV) out[obase + v0] = acc0[r] + bo;
        if (v1 < NV) out[obase + v1] = acc1[r] + bo;
    }
}

// ---------------------------------------------------------------------------
// Fallback (if ws too small): direct fp32 compute, slow but correct.
// ---------------------------------------------------------------------------
__global__ void naive_conv(const float* __restrict__ x, const int* __restrict__ idx,
                           const float* __restrict__ W, const float* __restrict__ bias,
                           float* __restrict__ out) {
    const int b = blockIdx.y;
    const int n = blockIdx.x * 4 + (threadIdx.x & 3);
    const int o = threadIdx.x >> 2;
    if (n >= NV) return;
    float acc = bias[o];
    const float* xb = x + (size_t)b * CI * NV;
    const float* wo = W + o * KKD;
    for (int k = 0; k < KN; ++k) {
        int j = idx[n * KN + k];
        for (int c = 0; c < CI; ++c)
            acc += xb[(size_t)c * NV + j] * wo[c * KN + k];
    }
    out[((size_t)b * CO + o) * NV + n] = acc;
}

// ---------------------------------------------------------------------------
extern "C" void kernel_launch(void* const* d_in, const int* in_sizes, int n_in,
                              void* d_out, int out_size, void* d_ws, size_t ws_size,
                              hipStream_t stream) {
    const float* x    = (const float*)d_in[0];
    const int*   idx  = (const int*)d_in[1];
    const float* W    = (const float*)d_in[2];
    const float* bias = (const float*)d_in[3];
    float* out = (float*)d_out;

    const size_t xT_bytes = (size_t)NV * 8 * CI * 2;        // 41,945,088 (interleaved)
    const size_t wf_bytes = (size_t)2 * 28 * 64 * 8 * 2;    // 57,344
    const size_t need = xT_bytes + wf_bytes;

    if (ws_size >= need) {
        u16* xTI = (u16*)d_ws;
        u16* Wf = (u16*)((char*)d_ws + xT_bytes);
        transpose_x<<<dim3((NV + 63) / 64, BB), 256, 0, stream>>>(x, xTI);
        pack_w<<<dim3(112), 256, 0, stream>>>(W, Wf);
        const int ntiles = (NV + 15) / 16;                   // 2561
        conv_mfma<<<dim3(ntiles), 256, 0, stream>>>(xTI, Wf, idx, bias, out);
    } else {
        naive_conv<<<dim3((NV + 3) / 4, BB), 256, 0, stream>>>(x, idx, W, bias, out);
    }
}

// Round 9
// 95.236 us; speedup vs baseline: 1.1370x; 1.1370x over previous
//
#include <hip/hip_runtime.h>

// Problem constants
#define BB 8
#define CI 64
#define CO 64
#define NV 40962
#define KN 7
#define KKD 448   // CI*KN

typedef unsigned short u16;
typedef unsigned int u32;

typedef __bf16 bf16x8 __attribute__((ext_vector_type(8)));
typedef float f32x16 __attribute__((ext_vector_type(16)));

__device__ inline u16 f2bf(float f) {
    u32 u = __builtin_bit_cast(u32, f);
    u32 r = (u + 0x7FFFu + ((u >> 16) & 1u)) >> 16;  // RNE
    return (u16)r;
}

// global 16B/lane -> LDS at (wave-uniform base + lane*16); dest linear.
__device__ inline void gload_lds16(const void* g, void* l) {
    __builtin_amdgcn_global_load_lds(
        (const __attribute__((address_space(1))) u32*)g,
        (__attribute__((address_space(3))) u32*)l, 16, 0, 0);
}

// ---------------------------------------------------------------------------
// Kernel 1: transpose + cast: x[b][c][n] f32 -> xTI[n][b][c] bf16.
// Vertex row n = 8 batches x 64 ch x 2B = 1 KB contiguous: one gathered
// neighbor = one coalesced 1 KB burst serving all 8 batches.
// ---------------------------------------------------------------------------
__global__ void transpose_x(const float* __restrict__ x, u16* __restrict__ xTI) {
    __shared__ u16 tile[64][72];
    const int b = blockIdx.y;
    const int n0 = blockIdx.x * 64;
    const int tid = threadIdx.x;

#pragma unroll
    for (int i = 0; i < 16; ++i) {
        int flat = i * 256 + tid;
        int c = flat >> 6;
        int nn = flat & 63;
        int n = n0 + nn;
        if (n < NV) {
            float v = __builtin_nontemporal_load(&x[((size_t)b * CI + c) * NV + n]);
            tile[nn][c] = f2bf(v);
        }
    }
    __syncthreads();

#pragma unroll
    for (int i = 0; i < 2; ++i) {
        int flat8 = i * 256 + tid;
        int nn = flat8 >> 3;
        int c0 = (flat8 & 7) * 8;
        int n = n0 + nn;
        if (n < NV) {
            uint4 v = *(const uint4*)&tile[nn][c0];
            *(uint4*)&xTI[((size_t)n * 8 + b) * 64 + c0] = v;   // [n][b][c]
        }
    }
}

// ---------------------------------------------------------------------------
// Kernel 2: pack W into MFMA A-fragment order (bf16)
// Wf byte offset (rg*28 + k*4 + s)*1024 + lane*16
// ---------------------------------------------------------------------------
__global__ void pack_w(const float* __restrict__ W, u16* __restrict__ Wf) {
    int e = blockIdx.x * 256 + threadIdx.x;
    if (e < 2 * 28 * 64 * 8) {
        int j = e & 7;
        int lane = (e >> 3) & 63;
        int sg = e >> 9;
        int s = sg % 28;
        int rg = sg / 28;
        int o = rg * 32 + (lane & 31);
        int kk = s * 16 + ((lane >> 5) << 3) + j;
        int kn = kk >> 6;
        int c = kk & 63;
        Wf[e] = f2bf(W[o * KKD + c * KN + kn]);
    }
}

// ---------------------------------------------------------------------------
// Kernel 3: batch-interleaved gather + MFMA GEMM with r6-quality writes.
// grid 1281 blocks, block 512 = 8 waves. Tile: 32 vertices x 8 batches x
// 64 outputs. Wave w: rg = w&1 (32 outs), cg = w>>1 (batches 2cg, 2cg+1).
// MFMA cols = 32 contiguous vertices of ONE batch -> epilogue stores are
// 2 x 128 B contiguous runs per instruction (measured 83 MB in r6).
// Gather: 32 rows x 1 KB per k, one gload_lds instr per row (all batches
// amortized, requests /8 vs r6/r7). LDS slot-XOR by row&7 (src pre-swizzle,
// linear dest, swizzled ds_read) -> conflict-free (8 dwords/bank minimum).
// Ring-2 x 32 KB; schedule per iter k (r6 race-proof):
//   issue A(k+1) -> vmcnt(4) [drains A(k)+G(k), keeps A(k+1)] -> s_barrier
//   -> issue G(k+1) into buf (k+1)&1 (readers finished at barrier)
//   -> compute buf k&1.
// ---------------------------------------------------------------------------
__global__ __launch_bounds__(512, 4) void conv_mfma(
    const u16* __restrict__ xTI, const u16* __restrict__ Wf,
    const int* __restrict__ idx, const float* __restrict__ bias,
    float* __restrict__ out) {
    __shared__ alignas(16) u16 G[2][16384];   // 2 x 32 KB; buffer = 32 rows x 1 KB

    const int bid = blockIdx.x;
    const int n0 = bid * 32;
    const int t = threadIdx.x;
    const int lane = t & 63;
    const int w = t >> 6;        // 0..7
    const int rg = w & 1;
    const int cg = w >> 1;       // 0..3
    const int col = lane & 31;   // vertex within tile
    const int half = lane >> 5;
    const int sl = lane & 7;     // staging slot within 128B segment

    const char* xbc = (const char*)xTI;
    const char* wfc = (const char*)Wf;
    char* gb = (char*)&G[0][0];

    // rows staged by this wave: lv = w*4+i; idx wave-uniform broadcast loads
    int jv[4][KN];
    u32 srcsw[4];
#pragma unroll
    for (int i = 0; i < 4; ++i) {
        int lv = w * 4 + i;
        int v = n0 + lv; if (v >= NV) v = NV - 1;
        int4 lo = *(const int4*)(idx + (size_t)v * KN);
        int4 hi = *(const int4*)(idx + (size_t)v * KN + 3);
        jv[i][0] = lo.x; jv[i][1] = lo.y; jv[i][2] = lo.z; jv[i][3] = lo.w;
        jv[i][4] = hi.y; jv[i][5] = hi.z; jv[i][6] = hi.w;
        // source pre-swizzle: lane reads chunk (sl ^ (row&7)) of its batch seg
        srcsw[i] = (u32)((lane >> 3) * 128) + (u32)((((sl ^ lv) & 7)) << 4);
    }
    const u32 dstb = (u32)((w * 4) * 1024);   // wave-uniform LDS dest base

    // B-read geometry: addr = col*1024 + b*128 + ((2s+half)^(col&7))*16
    const u32 rb0 = (u32)(col * 1024 + (cg * 2) * 128);
    u32 soff[4];
#pragma unroll
    for (int s = 0; s < 4; ++s)
        soff[s] = (u32)((((2 * s + half) ^ col) & 7) << 4);

    const u32 abase = (u32)((rg * 28) * 1024 + lane * 16);

    f32x16 acc0{}, acc1{};

    // ---- prologue: G(0) -> buf0, then A(0) ----
#pragma unroll
    for (int i = 0; i < 4; ++i)
        gload_lds16(xbc + (size_t)jv[i][0] * 1024 + srcsw[i],
                    gb + dstb + (u32)(i * 1024));
    __builtin_amdgcn_sched_barrier(0);
    uint4 acur0 = *(const uint4*)(wfc + abase + 0 * 1024);
    uint4 acur1 = *(const uint4*)(wfc + abase + 1 * 1024);
    uint4 acur2 = *(const uint4*)(wfc + abase + 2 * 1024);
    uint4 acur3 = *(const uint4*)(wfc + abase + 3 * 1024);
    __builtin_amdgcn_sched_barrier(0);

#pragma unroll
    for (int k = 0; k < KN; ++k) {
        // ---- issue A(k+1) (kept in flight across the wait) ----
        uint4 an0, an1, an2, an3;
        if (k + 1 < KN) {
            u32 ab = abase + (u32)((k + 1) * 4096);
            an0 = *(const uint4*)(wfc + ab + 0 * 1024);
            an1 = *(const uint4*)(wfc + ab + 1 * 1024);
            an2 = *(const uint4*)(wfc + ab + 2 * 1024);
            an3 = *(const uint4*)(wfc + ab + 3 * 1024);
        }
        __builtin_amdgcn_sched_barrier(0);

        // queue: [A(k)4, G(k)4, A(k+1)4] -> vmcnt(4) drains A(k)+G(k)
        if (k + 1 < KN) asm volatile("s_waitcnt vmcnt(4)" ::: "memory");
        else            asm volatile("s_waitcnt vmcnt(0)" ::: "memory");
        __builtin_amdgcn_sched_barrier(0);
        __builtin_amdgcn_s_barrier();
        __builtin_amdgcn_sched_barrier(0);

        // ---- issue G(k+1) AFTER barrier: buf (k+1)&1's readers (iter k-1)
        //      are provably done once all waves passed barrier k ----
        if (k + 1 < KN) {
            u32 db = (u32)(((k + 1) & 1) * 32768);
#pragma unroll
            for (int i = 0; i < 4; ++i)
                gload_lds16(xbc + (size_t)jv[i][k + 1] * 1024 + srcsw[i],
                            gb + db + dstb + (u32)(i * 1024));
        }
        __builtin_amdgcn_sched_barrier(0);

        // ---- compute on buffer k&1: 2 batches x 4 K-steps = 8 MFMA ----
        const char* gsrc = gb + (u32)((k & 1) * 32768);
#pragma unroll
        for (int s = 0; s < 4; ++s) {
            uint4 b0 = *(const uint4*)(gsrc + rb0 + soff[s]);
            uint4 b1 = *(const uint4*)(gsrc + rb0 + 128 + soff[s]);
            uint4 af = (s == 0) ? acur0 : (s == 1) ? acur1 : (s == 2) ? acur2 : acur3;
            acc0 = __builtin_amdgcn_mfma_f32_32x32x16_bf16(
                __builtin_bit_cast(bf16x8, af), __builtin_bit_cast(bf16x8, b0), acc0, 0, 0, 0);
            acc1 = __builtin_amdgcn_mfma_f32_32x32x16_bf16(
                __builtin_bit_cast(bf16x8, af), __builtin_bit_cast(bf16x8, b1), acc1, 0, 0, 0);
        }

        if (k + 1 < KN) { acur0 = an0; acur1 = an1; acur2 = an2; acur3 = an3; }
    }

    // ---- epilogue: per instruction 2 x 128 B contiguous runs, plain stores
    const int vcol = n0 + col;
    const int b0 = cg * 2, b1 = b0 + 1;
    if (vcol < NV) {
#pragma unroll
        for (int r = 0; r < 16; ++r) {
            int rowo = (r & 3) + 8 * (r >> 2) + 4 * half;
            int o = rg * 32 + rowo;
            float bo = bias[o];
            out[((size_t)(b0 * CO + o)) * NV + vcol] = acc0[r] + bo;
            out[((size_t)(b1 * CO + o)) * NV + vcol] = acc1[r] + bo;
        }
    }
}

// ---------------------------------------------------------------------------
// Fallback (if ws too small): direct fp32 compute, slow but correct.
// ---------------------------------------------------------------------------
__global__ void naive_conv(const float* __restrict__ x, const int* __restrict__ idx,
                           const float* __restrict__ W, const float* __restrict__ bias,
                           float* __restrict__ out) {
    const int b = blockIdx.y;
    const int n = blockIdx.x * 4 + (threadIdx.x & 3);
    const int o = threadIdx.x >> 2;
    if (n >= NV) return;
    float acc = bias[o];
    const float* xb = x + (size_t)b * CI * NV;
    const float* wo = W + o * KKD;
    for (int k = 0; k < KN; ++k) {
        int j = idx[n * KN + k];
        for (int c = 0; c < CI; ++c)
            acc += xb[(size_t)c * NV + j] * wo[c * KN + k];
    }
    out[((size_t)b * CO + o) * NV + n] = acc;
}

// ---------------------------------------------------------------------------
extern "C" void kernel_launch(void* const* d_in, const int* in_sizes, int n_in,
                              void* d_out, int out_size, void* d_ws, size_t ws_size,
                              hipStream_t stream) {
    const float* x    = (const float*)d_in[0];
    const int*   idx  = (const int*)d_in[1];
    const float* W    = (const float*)d_in[2];
    const float* bias = (const float*)d_in[3];
    float* out = (float*)d_out;

    const size_t xT_bytes = (size_t)NV * 8 * CI * 2;        // 41,945,088 (interleaved)
    const size_t wf_bytes = (size_t)2 * 28 * 64 * 8 * 2;    // 57,344
    const size_t need = xT_bytes + wf_bytes;

    if (ws_size >= need) {
        u16* xTI = (u16*)d_ws;
        u16* Wf = (u16*)((char*)d_ws + xT_bytes);
        transpose_x<<<dim3((NV + 63) / 64, BB), 256, 0, stream>>>(x, xTI);
        pack_w<<<dim3(112), 256, 0, stream>>>(W, Wf);
        const int ntiles = (NV + 31) / 32;                   // 1281
        conv_mfma<<<dim3(ntiles), 512, 0, stream>>>(xTI, Wf, idx, bias, out);
    } else {
        naive_conv<<<dim3((NV + 3) / 4, BB), 256, 0, stream>>>(x, idx, W, bias, out);
    }
}

// Round 10
// 81.544 us; speedup vs baseline: 1.3279x; 1.1679x over previous
//
#include <hip/hip_runtime.h>

// Problem constants
#define BB 8
#define CI 64
#define CO 64
#define NV 40962
#define KN 7
#define KKD 448   // CI*KN

typedef unsigned short u16;
typedef unsigned int u32;

typedef __bf16 bf16x8 __attribute__((ext_vector_type(8)));
typedef float f32x16 __attribute__((ext_vector_type(16)));

__device__ inline u16 f2bf(float f) {
    u32 u = __builtin_bit_cast(u32, f);
    u32 r = (u + 0x7FFFu + ((u >> 16) & 1u)) >> 16;  // RNE
    return (u16)r;
}

// global 16B/lane -> LDS at (wave-uniform base + lane*16); dest linear.
__device__ inline void gload_lds16(const void* g, void* l) {
    __builtin_amdgcn_global_load_lds(
        (const __attribute__((address_space(1))) u32*)g,
        (__attribute__((address_space(3))) u32*)l, 16, 0, 0);
}

// ---------------------------------------------------------------------------
// Kernel 1: transpose + bf16 cast:  x[b][c][n] f32  ->  xT[b][n][c] bf16
// (r6 layout: 128B row per (b,n); batch-pinned gather keeps 5.2MB/XCD in L2)
// ---------------------------------------------------------------------------
__global__ void transpose_x(const float* __restrict__ x, u16* __restrict__ xT) {
    __shared__ u16 tile[64][72];
    const int b = blockIdx.y;
    const int n0 = blockIdx.x * 64;
    const int tid = threadIdx.x;

#pragma unroll
    for (int i = 0; i < 16; ++i) {
        int flat = i * 256 + tid;
        int c = flat >> 6;
        int nn = flat & 63;
        int n = n0 + nn;
        if (n < NV) {
            float v = __builtin_nontemporal_load(&x[((size_t)b * CI + c) * NV + n]);
            tile[nn][c] = f2bf(v);
        }
    }
    __syncthreads();

#pragma unroll
    for (int i = 0; i < 2; ++i) {
        int flat8 = i * 256 + tid;
        int nn = flat8 >> 3;
        int c0 = (flat8 & 7) * 8;
        int n = n0 + nn;
        if (n < NV) {
            uint4 v = *(const uint4*)&tile[nn][c0];
            *(uint4*)&xT[((size_t)b * NV + n) * CI + c0] = v;
        }
    }
}

// ---------------------------------------------------------------------------
// Kernel 2: pack W into MFMA A-fragment order (bf16)
// Wf byte offset (rg*28 + k*4 + sub)*1024 + lane*16
// ---------------------------------------------------------------------------
__global__ void pack_w(const float* __restrict__ W, u16* __restrict__ Wf) {
    int e = blockIdx.x * 256 + threadIdx.x;
    if (e < 2 * 28 * 64 * 8) {
        int j = e & 7;
        int lane = (e >> 3) & 63;
        int sg = e >> 9;
        int s = sg % 28;
        int rg = sg / 28;
        int o = rg * 32 + (lane & 31);
        int kk = s * 16 + ((lane >> 5) << 3) + j;
        int kn = kk >> 6;
        int c = kk & 63;
        Wf[e] = f2bf(W[o * KKD + c * KN + kn]);
    }
}

// ---------------------------------------------------------------------------
// Kernel 3: FULLY DECOUPLED per-wave gather+MFMA. NO barriers of any kind.
// grid 1-D: b = bid&7 (XCD pin), n0 = (bid>>3)*128. block 256 = 4 waves.
// Wave wv owns vertices [n0+wv*32, +32) x ALL 64 outputs of batch b.
// Per k: 4 x gload_lds (8 rows x 128B, source pre-swizzled), wave-private
// ring-3 (3 x 4KB). A(k+1) prefetched to regs in the same counted stream.
// Ring-3 WAR safety: slot (k+2)%3 was last ds_read at iter k-1, and those
// reads completed (lgkmcnt) before its MFMAs -- program order within the
// wave guarantees the overwrite at iter k is safe. No cross-wave sharing.
// vmcnt ladder (in-flight entering iter k = G(k)4+A(k)8+G(k+1)4 = 16;
// issue A(k+1)8+G(k+2)4 -> 28; retire G(k)+A(k) -> keep 16):
//   k<=4: vmcnt(16); k==5 (no G(7)): vmcnt(12); k==6: vmcnt(0).
// ---------------------------------------------------------------------------
__global__ __launch_bounds__(256, 3) void conv_mfma(
    const u16* __restrict__ xT, const u16* __restrict__ Wf,
    const int* __restrict__ idx, const float* __restrict__ bias,
    float* __restrict__ out) {
    __shared__ alignas(16) u16 G[4][3][2048];   // 4 waves x ring-3 x 4KB = 48KB

    const int bid = blockIdx.x;
    const int b = bid & 7;
    const int n0 = (bid >> 3) * 128;
    const int t = threadIdx.x;
    const int lane = t & 63;
    const int wv = t >> 6;       // 0..3
    const int col = lane & 31;   // vertex within wave tile
    const int half = lane >> 5;

    const char* xbc = (const char*)(xT + (size_t)b * NV * CI);
    const char* wfc = (const char*)Wf;
    char* gw = (char*)&G[wv][0][0];

    // staging: instr i covers rows i*8 + (lane>>3); 8 lanes per row.
    const int srow = lane >> 3;             // 0..7
    const u32 srcq = (u32)(((lane & 7) ^ srow) << 4);   // chunk pre-swizzle by row&7

    // neighbor indices for this lane's 4 staged rows (28 VGPR)
    int jv[4][KN];
#pragma unroll
    for (int i = 0; i < 4; ++i) {
        int v = n0 + wv * 32 + i * 8 + srow;
        if (v >= NV) v = NV - 1;
        int4 lo = *(const int4*)(idx + (size_t)v * KN);
        int4 hi = *(const int4*)(idx + (size_t)v * KN + 3);
        jv[i][0] = lo.x; jv[i][1] = lo.y; jv[i][2] = lo.z; jv[i][3] = lo.w;
        jv[i][4] = hi.y; jv[i][5] = hi.z; jv[i][6] = hi.w;
    }

    // B-read geometry (within 4KB ring slot): row col, slot (2s+half)^(col&7)
    const u32 rbase = (u32)(col * 128);
    const u32 rmask = (u32)(col & 7) << 4;

    const u32 abase = (u32)(lane * 16);

    f32x16 acc0{}, acc1{};   // rg0 (outs 0-31), rg1 (outs 32-63)

#define STAGE_G(kk, ring)                                                     \
    {                                                                         \
        char* d = gw + (u32)((ring) * 4096);                                  \
        _Pragma("unroll")                                                     \
        for (int i = 0; i < 4; ++i)                                           \
            gload_lds16(xbc + (size_t)jv[i][kk] * 128 + srcq,                 \
                        d + (u32)(i * 1024));                                 \
    }

#define LOAD_A(kk, r0, r1, r2, r3, r4, r5, r6, r7)                            \
    {                                                                         \
        u32 a0 = abase + (u32)((0 * 28 + (kk) * 4) * 1024);                   \
        u32 a1 = abase + (u32)((1 * 28 + (kk) * 4) * 1024);                   \
        r0 = *(const uint4*)(wfc + a0 + 0 * 1024);                            \
        r1 = *(const uint4*)(wfc + a0 + 1 * 1024);                            \
        r2 = *(const uint4*)(wfc + a0 + 2 * 1024);                            \
        r3 = *(const uint4*)(wfc + a0 + 3 * 1024);                            \
        r4 = *(const uint4*)(wfc + a1 + 0 * 1024);                            \
        r5 = *(const uint4*)(wfc + a1 + 1 * 1024);                            \
        r6 = *(const uint4*)(wfc + a1 + 2 * 1024);                            \
        r7 = *(const uint4*)(wfc + a1 + 3 * 1024);                            \
    }

    uint4 cA0, cA1, cA2, cA3, cB0, cB1, cB2, cB3;
    uint4 nA0, nA1, nA2, nA3, nB0, nB1, nB2, nB3;

    // ---- prologue: G(0), A(0), G(1)  (issue order pinned) ----
    STAGE_G(0, 0);
    __builtin_amdgcn_sched_barrier(0);
    LOAD_A(0, cA0, cA1, cA2, cA3, cB0, cB1, cB2, cB3);
    __builtin_amdgcn_sched_barrier(0);
    STAGE_G(1, 1);
    __builtin_amdgcn_sched_barrier(0);

#pragma unroll
    for (int k = 0; k < KN; ++k) {
        // ---- issue A(k+1) ----
        if (k + 1 < KN) {
            LOAD_A(k + 1, nA0, nA1, nA2, nA3, nB0, nB1, nB2, nB3);
        }
        __builtin_amdgcn_sched_barrier(0);
        // ---- issue G(k+2) into ring (k+2)%3 (wave-private WAR-safe) ----
        if (k + 2 < KN) {
            STAGE_G(k + 2, (k + 2) % 3);
        }
        __builtin_amdgcn_sched_barrier(0);

        // ---- per-wave counted wait (no barrier!) ----
        if (k <= 4)      asm volatile("s_waitcnt vmcnt(16)" ::: "memory");
        else if (k == 5) asm volatile("s_waitcnt vmcnt(12)" ::: "memory");
        else             asm volatile("s_waitcnt vmcnt(0)" ::: "memory");
        __builtin_amdgcn_sched_barrier(0);

        // ---- compute on ring k%3: 4 K-steps x 2 out-groups = 8 MFMA ----
        const char* gsrc = gw + (u32)((k % 3) * 4096);
#pragma unroll
        for (int s = 0; s < 4; ++s) {
            u32 boff = rbase + ((((u32)s * 32) + (u32)half * 16) ^ rmask);
            uint4 bf = *(const uint4*)(gsrc + boff);
            uint4 a0 = (s == 0) ? cA0 : (s == 1) ? cA1 : (s == 2) ? cA2 : cA3;
            uint4 a1 = (s == 0) ? cB0 : (s == 1) ? cB1 : (s == 2) ? cB2 : cB3;
            acc0 = __builtin_amdgcn_mfma_f32_32x32x16_bf16(
                __builtin_bit_cast(bf16x8, a0), __builtin_bit_cast(bf16x8, bf), acc0, 0, 0, 0);
            acc1 = __builtin_amdgcn_mfma_f32_32x32x16_bf16(
                __builtin_bit_cast(bf16x8, a1), __builtin_bit_cast(bf16x8, bf), acc1, 0, 0, 0);
        }

        if (k + 1 < KN) {
            cA0 = nA0; cA1 = nA1; cA2 = nA2; cA3 = nA3;
            cB0 = nB0; cB1 = nB1; cB2 = nB2; cB3 = nB3;
        }
    }
#undef STAGE_G
#undef LOAD_A

    // ---- epilogue: r6-quality contiguous 128B-run stores ----
    const int v = n0 + wv * 32 + col;
    if (v < NV) {
        float* ob = out + (size_t)b * CO * NV + v;
#pragma unroll
        for (int r = 0; r < 16; ++r) {
            int rowo = (r & 3) + 8 * (r >> 2) + 4 * half;
            ob[(size_t)rowo * NV] = acc0[r] + bias[rowo];
            ob[(size_t)(32 + rowo) * NV] = acc1[r] + bias[32 + rowo];
        }
    }
}

// ---------------------------------------------------------------------------
// Fallback (if ws too small): direct fp32 compute, slow but correct.
// ---------------------------------------------------------------------------
__global__ void naive_conv(const float* __restrict__ x, const int* __restrict__ idx,
                           const float* __restrict__ W, const float* __restrict__ bias,
                           float* __restrict__ out) {
    const int b = blockIdx.y;
    const int n = blockIdx.x * 4 + (threadIdx.x & 3);
    const int o = threadIdx.x >> 2;
    if (n >= NV) return;
    float acc = bias[o];
    const float* xb = x + (size_t)b * CI * NV;
    const float* wo = W + o * KKD;
    for (int k = 0; k < KN; ++k) {
        int j = idx[n * KN + k];
        for (int c = 0; c < CI; ++c)
            acc += xb[(size_t)c * NV + j] * wo[c * KN + k];
    }
    out[((size_t)b * CO + o) * NV + n] = acc;
}

// ---------------------------------------------------------------------------
extern "C" void kernel_launch(void* const* d_in, const int* in_sizes, int n_in,
                              void* d_out, int out_size, void* d_ws, size_t ws_size,
                              hipStream_t stream) {
    const float* x    = (const float*)d_in[0];
    const int*   idx  = (const int*)d_in[1];
    const float* W    = (const float*)d_in[2];
    const float* bias = (const float*)d_in[3];
    float* out = (float*)d_out;

    const size_t xT_bytes = (size_t)BB * NV * CI * 2;       // 41,945,088
    const size_t wf_bytes = (size_t)2 * 28 * 64 * 8 * 2;    // 57,344
    const size_t need = xT_bytes + wf_bytes;

    if (ws_size >= need) {
        u16* xT = (u16*)d_ws;
        u16* Wf = (u16*)((char*)d_ws + xT_bytes);
        transpose_x<<<dim3((NV + 63) / 64, BB), 256, 0, stream>>>(x, xT);
        pack_w<<<dim3(112), 256, 0, stream>>>(W, Wf);
        const int ntiles = (NV + 127) / 128;                 // 321
        conv_mfma<<<dim3(ntiles * BB), 256, 0, stream>>>(xT, Wf, idx, bias, out);
    } else {
        naive_conv<<<dim3((NV + 3) / 4, BB), 256, 0, stream>>>(x, idx, W, bias, out);
    }
}